// Round 9
// baseline (991.635 us; speedup 1.0000x reference)
//
#include <hip/hip_runtime.h>
#include <hip/hip_bf16.h>

// CustomRNN: h_{t+1} = tanh([x_t | h_t] @ W_ih + b_ih), out = h_final @ W_ho + b_ho
// BATCH=512, SEQ=1024, IN=64, HID=256, CLS=10.
//
// 512 blocks x 512 threads (8 waves), ONE batch row per block, TWO blocks
// co-resident per CU (4 waves/SIMD). R8 proved the single-domain structure
// clean (VGPR 108, conflicts ~0) but its step was ~1240 cyc vs ~450 cyc of
// pipe work: one barrier domain leaves the serial chain (ds_read latency ->
// MFMA chain -> tanh -> barrier) unfilled. R5 proved two drifting barrier
// domains per CU reach MfmaUtil 64% but died of register spill. This merges
// them: R8's 32-cols-per-wave layout (20 B-frags = 80 VGPR, fits the
// 128-reg tier) x 2 blocks/CU.
//
//  - W_ih pre-scaled by 2*log2(e), register-resident B-frags; wave w owns
//    paired cols 32w+2f, 32w+2f+1.
//  - LDS interleaved [kt][32elem] layout; A-reads exec-masked to frow==0
//    (4 lanes, 16 distinct banks, conflict-free); h-write packed u32.
//  - Split accumulator chains (even/odd kt): dependent depth 5.
//  - x: 2-step register prefetch by wave 0, tiny LDS panel, bf16.
//  - Barrier: raw `s_waitcnt lgkmcnt(0); s_barrier` (vmcnt stays in flight).
//  - s_setprio(1) around the MFMA cluster (two domains -> role diversity).

#define BATCH 512
#define SEQ   1024
#define INP   64
#define HID   256
#define CLS   10
#define NTHREADS 512
#define TSCALE 2.8853900817779268f // 2*log2(e), folded into W_ih/b_ih

typedef short bf16x8 __attribute__((ext_vector_type(8)));
typedef float f32x4  __attribute__((ext_vector_type(4)));

static __device__ __forceinline__ unsigned short f2bf(float f) {
  __hip_bfloat16 h = __float2bfloat16(f);   // RNE
  return *reinterpret_cast<unsigned short*>(&h);
}
static __device__ __forceinline__ float bf2f(unsigned short b) {
  union { unsigned int u; float f; } v; v.u = ((unsigned int)b) << 16;
  return v.f;
}
static __device__ __forceinline__ unsigned int cvt_pk_bf16(float lo, float hi) {
  unsigned int r;
  asm("v_cvt_pk_bf16_f32 %0, %1, %2" : "=v"(r) : "v"(lo), "v"(hi));
  return r;
}
static __device__ __forceinline__ float fast_exp2(float x) {
#if __has_builtin(__builtin_amdgcn_exp2f)
  return __builtin_amdgcn_exp2f(x);
#else
  return __exp2f(x);
#endif
}
static __device__ __forceinline__ float fast_rcp(float x) {
#if __has_builtin(__builtin_amdgcn_rcpf)
  return __builtin_amdgcn_rcpf(x);
#else
  return 1.0f / x;
#endif
}
// pre-activation already scaled by 2*log2(e): tanh(x) = 1 - 2/(1 + exp2(s)).
static __device__ __forceinline__ float tanh_scaled(float s) {
  return 1.0f - 2.0f * fast_rcp(1.0f + fast_exp2(s));
}

#define MFMA16(A, B, C) __builtin_amdgcn_mfma_f32_16x16x32_bf16(A, B, C, 0, 0, 0)

// Drain LDS ops only; in-flight global x loads (vmcnt) stay pending.
#define BARRIER() asm volatile("s_waitcnt lgkmcnt(0)\n\ts_barrier" ::: "memory")

// One scan step (reads buf CUR, writes buf CUR^1, one barrier).
// aP0,aP1,aQ0,aQ1: persistent frag regs; masked lanes (frow!=0) keep stale
// data — harmless, D rows 1-15 are padding. Chains: *a = even kt, *b = odd.
#define STEP(T, CUR, XR) do {                                                   \
    /* stage x(T+1) (in XR, loaded 2 steps ago) -> sX[CUR^1]; XR = x(T+3) */    \
    if (wave == 0 && lane < 32) {                                               \
      ((unsigned int*)sX[(CUR) ^ 1])[(lane >> 4) * 16 + (lane & 15)]            \
          = cvt_pk_bf16(XR.x, XR.y);                                            \
      int tn_ = (T) + 3; tn_ = tn_ < SEQ ? tn_ : SEQ - 1;                       \
      XR = *(const float2*)&xstage[(size_t)tn_ * INP];                          \
    }                                                                           \
    f32x4 acc0a = {bias0, bias0, bias0, bias0};                                 \
    f32x4 acc1a = {bias1, bias1, bias1, bias1};                                 \
    f32x4 acc0b = {0.f, 0.f, 0.f, 0.f};                                         \
    f32x4 acc1b = {0.f, 0.f, 0.f, 0.f};                                         \
    /* masked A-reads: only frow==0 lanes carry the real row */                 \
    if (frow == 0) {                                                            \
      aP0 = *(const bf16x8*)&sX[CUR][0][g8];                                    \
      aP1 = *(const bf16x8*)&sX[CUR][1][g8];                                    \
      aQ0 = *(const bf16x8*)&sH[CUR][0][g8];                                    \
      aQ1 = *(const bf16x8*)&sH[CUR][1][g8];                                    \
    }                                                                           \
    __builtin_amdgcn_s_setprio(1);                                              \
    acc0a = MFMA16(aP0, bw[0][0], acc0a); acc1a = MFMA16(aP0, bw[0][1], acc1a); \
    acc0b = MFMA16(aP1, bw[1][0], acc0b); acc1b = MFMA16(aP1, bw[1][1], acc1b); \
    __builtin_amdgcn_sched_barrier(0);                                          \
    if (frow == 0) {                                                            \
      aP0 = *(const bf16x8*)&sH[CUR][2][g8];                                    \
      aP1 = *(const bf16x8*)&sH[CUR][3][g8];                                    \
    }                                                                           \
    acc0a = MFMA16(aQ0, bw[2][0], acc0a); acc1a = MFMA16(aQ0, bw[2][1], acc1a); \
    acc0b = MFMA16(aQ1, bw[3][0], acc0b); acc1b = MFMA16(aQ1, bw[3][1], acc1b); \
    __builtin_amdgcn_sched_barrier(0);                                          \
    if (frow == 0) {                                                            \
      aQ0 = *(const bf16x8*)&sH[CUR][4][g8];                                    \
      aQ1 = *(const bf16x8*)&sH[CUR][5][g8];                                    \
    }                                                                           \
    acc0a = MFMA16(aP0, bw[4][0], acc0a); acc1a = MFMA16(aP0, bw[4][1], acc1a); \
    acc0b = MFMA16(aP1, bw[5][0], acc0b); acc1b = MFMA16(aP1, bw[5][1], acc1b); \
    __builtin_amdgcn_sched_barrier(0);                                          \
    if (frow == 0) {                                                            \
      aP0 = *(const bf16x8*)&sH[CUR][6][g8];                                    \
      aP1 = *(const bf16x8*)&sH[CUR][7][g8];                                    \
    }                                                                           \
    acc0a = MFMA16(aQ0, bw[6][0], acc0a); acc1a = MFMA16(aQ0, bw[6][1], acc1a); \
    acc0b = MFMA16(aQ1, bw[7][0], acc0b); acc1b = MFMA16(aQ1, bw[7][1], acc1b); \
    __builtin_amdgcn_sched_barrier(0);                                          \
    acc0a = MFMA16(aP0, bw[8][0], acc0a); acc1a = MFMA16(aP0, bw[8][1], acc1a); \
    acc0b = MFMA16(aP1, bw[9][0], acc0b); acc1b = MFMA16(aP1, bw[9][1], acc1b); \
    __builtin_amdgcn_s_setprio(0);                                              \
    /* D: col=lane&15, row=4g+j -> row 0 lives in g==0, j==0 */                 \
    float t00 = tanh_scaled(acc0a[0] + acc0b[0]);   /* col 32w+2f   */          \
    float t10 = tanh_scaled(acc1a[0] + acc1b[0]);   /* col 32w+2f+1 */          \
    if (g == 0) {                                                               \
      /* col pair (2f,2f+1) of chunk `wave` -> dword wave*16 + f */             \
      ((unsigned int*)sH[(CUR) ^ 1])[wave * 16 + frow] = cvt_pk_bf16(t00, t10); \
    }                                                                           \
    BARRIER();                                                                  \
  } while (0)

__global__ __launch_bounds__(NTHREADS, 2)
void rnn_scan_kernel(const float* __restrict__ x,
                     const float* __restrict__ W_ih,
                     const float* __restrict__ b_ih,
                     const float* __restrict__ W_ho,
                     const float* __restrict__ b_ho,
                     float* __restrict__ out) {
  // Interleaved layout: [buf][kt-chunk][32 elems]; element c of the logical
  // 256-wide h lives at sH[buf][c>>5][c&31]. Masked A-read (4 lanes, g=0..3)
  // hits bytes kt*64 + 16g -> 16 distinct banks, conflict-free.
  __shared__ __align__(16) unsigned short sH[2][8][32];  // 2 x 512 B
  __shared__ __align__(16) unsigned short sX[2][2][32];  // 2 x 128 B

  const int tid  = threadIdx.x;
  const int lane = tid & 63;
  const int wave = tid >> 6;          // 0..7
  const int row  = blockIdx.x;        // one batch row per block

  const int g    = (lane >> 4) & 3;   // k-group within fragment
  const int g8   = g * 8;             // element offset within k-tile chunk
  const int frow = lane & 15;         // A-row (reads) / B,D tile-col

  // ---- Preload W_ih as B-fragments (bf16, pre-scaled by TSCALE).
  // Tile q: global col = 32*wave + 2*frow + q. Lane (g,f): B[kt*32+8g+i][f].
  bf16x8 bw[10][2];
  const int colE = 32 * wave + 2 * frow;
  const float bias0 = b_ih[colE] * TSCALE;
  const float bias1 = b_ih[colE + 1] * TSCALE;
#pragma unroll
  for (int q = 0; q < 2; ++q) {
#pragma unroll
    for (int kt = 0; kt < 10; ++kt) {
      bf16x8 v;
#pragma unroll
      for (int i = 0; i < 8; ++i)
        v[i] = (short)f2bf(W_ih[(size_t)(kt * 32 + g * 8 + i) * HID + colE + q] * TSCALE);
      bw[kt][q] = v;
    }
  }

  // ---- x staging: wave 0, lanes 0..31; lane l holds cols 2l, 2l+1.
  const float* xstage = x + (size_t)row * SEQ * INP + lane * 2;
  float2 xrA = make_float2(0.f, 0.f), xrB = make_float2(0.f, 0.f);

  // ---- Persistent A-frag registers (masked lanes keep stale copies).
  bf16x8 aP0 = {}, aP1 = {}, aQ0 = {}, aQ1 = {};

  // ---- Prologue: h(0)=0; stage x(0) -> sX[0]; xrA=x(1), xrB=x(2).
  if (tid < 128) ((unsigned int*)sH[0])[tid] = 0u;
  if (wave == 0 && lane < 32) {
    float2 v0 = *(const float2*)&xstage[0];
    ((unsigned int*)sX[0])[(lane >> 4) * 16 + (lane & 15)]
        = cvt_pk_bf16(v0.x, v0.y);
    xrA = *(const float2*)&xstage[(size_t)1 * INP];
    xrB = *(const float2*)&xstage[(size_t)2 * INP];
  }
  BARRIER();

  // ---- Main scan: unroll-2 -> static buffer flip + x-register rotation.
#pragma unroll 1
  for (int t = 0; t < SEQ; t += 2) {
    STEP(t,     0, xrA);
    STEP(t + 1, 1, xrB);
  }
  // SEQ even -> h_final in sH[0]

  // ---- Head: out[row] = h_final @ W_ho + b_ho (10 cols, once per block).
  if (tid < CLS) {
    const int cl = tid;
    float s = b_ho[cl];
#pragma unroll 8
    for (int k = 0; k < HID; ++k)
      s += bf2f(sH[0][k >> 5][k & 31]) * W_ho[(size_t)k * CLS + cl];
    out[(size_t)row * CLS + cl] = s;
  }
}

extern "C" void kernel_launch(void* const* d_in, const int* in_sizes, int n_in,
                              void* d_out, int out_size, void* d_ws, size_t ws_size,
                              hipStream_t stream) {
  const float* x    = (const float*)d_in[0];
  const float* W_ih = (const float*)d_in[1];
  const float* b_ih = (const float*)d_in[2];
  const float* W_ho = (const float*)d_in[3];
  const float* b_ho = (const float*)d_in[4];
  float* out = (float*)d_out;

  rnn_scan_kernel<<<BATCH, NTHREADS, 0, stream>>>(x, W_ih, b_ih, W_ho, b_ho, out);
}

// Round 10
// 598.480 us; speedup vs baseline: 1.6569x; 1.6569x over previous
//
#include <hip/hip_runtime.h>
#include <hip/hip_bf16.h>

// CustomRNN: h_{t+1} = tanh([x_t | h_t] @ W_ih + b_ih), out = h_final @ W_ho + b_ho
// BATCH=512, SEQ=1024, IN=64, HID=256, CLS=10.
//
// 256 blocks x 256 threads (4 waves = 1 wave/SIMD), TWO batch rows per block,
// one block per CU. Empirical law from R8/R9 (step 1240 cyc at 2 waves/SIMD,
// 2480 at 4): the per-step serial chain is DILUTED linearly by waves/SIMD —
// co-resident waves stretch, not fill, each other's chain. So run the limit
// case: ONE wave per SIMD, each wave owning 64 output cols.
//
//  - Wave w owns cols [64w,64w+64) as 4 sub-tiles (p,q): col = 64w+32p+2f+q.
//    W_ih pre-scaled by 2*log2(e): bw[10][2][2] = 40 bf16x8 frags = 160 VGPR.
//  - Register budget: launch_bounds(256) + amdgpu_waves_per_eu(1) -> cap 512,
//    demand ~230, NO spill (R5/R6's failure mode), no tier fight.
//  - LDS interleaved [kt][row][32elem]; A-reads exec-masked to frow<2
//    (8 lanes, 8 distinct banks -> conflict-free). h-writes packed u32.
//  - x: 2-step register prefetch by wave 0 into a tiny LDS panel.
//  - Barrier: raw `s_waitcnt lgkmcnt(0); s_barrier` (vmcnt stays in flight).
//  - No setprio (1 wave/SIMD: nothing to arbitrate).

#define BATCH 512
#define SEQ   1024
#define INP   64
#define HID   256
#define CLS   10
#define NTHREADS 256
#define TSCALE 2.8853900817779268f // 2*log2(e), folded into W_ih/b_ih

typedef short bf16x8 __attribute__((ext_vector_type(8)));
typedef float f32x4  __attribute__((ext_vector_type(4)));

static __device__ __forceinline__ unsigned short f2bf(float f) {
  __hip_bfloat16 h = __float2bfloat16(f);   // RNE
  return *reinterpret_cast<unsigned short*>(&h);
}
static __device__ __forceinline__ float bf2f(unsigned short b) {
  union { unsigned int u; float f; } v; v.u = ((unsigned int)b) << 16;
  return v.f;
}
static __device__ __forceinline__ unsigned int cvt_pk_bf16(float lo, float hi) {
  unsigned int r;
  asm("v_cvt_pk_bf16_f32 %0, %1, %2" : "=v"(r) : "v"(lo), "v"(hi));
  return r;
}
static __device__ __forceinline__ float fast_exp2(float x) {
#if __has_builtin(__builtin_amdgcn_exp2f)
  return __builtin_amdgcn_exp2f(x);
#else
  return __exp2f(x);
#endif
}
static __device__ __forceinline__ float fast_rcp(float x) {
#if __has_builtin(__builtin_amdgcn_rcpf)
  return __builtin_amdgcn_rcpf(x);
#else
  return 1.0f / x;
#endif
}
// pre-activation already scaled by 2*log2(e): tanh(x) = 1 - 2/(1 + exp2(s)).
static __device__ __forceinline__ float tanh_scaled(float s) {
  return 1.0f - 2.0f * fast_rcp(1.0f + fast_exp2(s));
}

#define MFMA16(A, B, C) __builtin_amdgcn_mfma_f32_16x16x32_bf16(A, B, C, 0, 0, 0)

// Drain LDS ops only; in-flight global x loads (vmcnt) stay pending.
#define BARRIER() asm volatile("s_waitcnt lgkmcnt(0)\n\ts_barrier" ::: "memory")

// 8 MFMAs of one k-fragment into the 4 (p,q) accumulators.
#define MF8(AF, KT)                                                             \
    acc00 = MFMA16(AF, bw[KT][0][0], acc00);                                    \
    acc01 = MFMA16(AF, bw[KT][0][1], acc01);                                    \
    acc10 = MFMA16(AF, bw[KT][1][0], acc10);                                    \
    acc11 = MFMA16(AF, bw[KT][1][1], acc11)

// One scan step (reads buf CUR, writes buf CUR^1, one barrier).
// aP0,aP1,aQ0,aQ1: persistent frag regs; masked lanes (frow>=2) keep stale
// data — harmless, D rows 2-15 are padding.
#define STEP(T, CUR, XR) do {                                                   \
    /* stage x(T+1) (in XR, loaded 2 steps ago) -> sX[CUR^1]; XR = x(T+3) */    \
    if (wave == 0) {                                                            \
      ((unsigned int*)sX[(CUR) ^ 1])[((xcp >> 4) * 2 + xrow) * 16 + (xcp & 15)] \
          = cvt_pk_bf16(XR.x, XR.y);                                            \
      int tn_ = (T) + 3; tn_ = tn_ < SEQ ? tn_ : SEQ - 1;                       \
      XR = *(const float2*)&xstage[(size_t)tn_ * INP];                          \
    }                                                                           \
    f32x4 acc00 = {bias00, bias00, 0.f, 0.f};                                   \
    f32x4 acc01 = {bias01, bias01, 0.f, 0.f};                                   \
    f32x4 acc10 = {bias10, bias10, 0.f, 0.f};                                   \
    f32x4 acc11 = {bias11, bias11, 0.f, 0.f};                                   \
    /* masked A-reads: only lanes frow<2 carry real rows */                     \
    if (frow < 2) {                                                             \
      aP0 = *(const bf16x8*)&sX[CUR][0][frow][g8];                              \
      aP1 = *(const bf16x8*)&sX[CUR][1][frow][g8];                              \
      aQ0 = *(const bf16x8*)&sH[CUR][0][frow][g8];                              \
      aQ1 = *(const bf16x8*)&sH[CUR][1][frow][g8];                              \
    }                                                                           \
    MF8(aP0, 0); MF8(aP1, 1);                                                   \
    __builtin_amdgcn_sched_barrier(0);                                          \
    if (frow < 2) {                                                             \
      aP0 = *(const bf16x8*)&sH[CUR][2][frow][g8];                              \
      aP1 = *(const bf16x8*)&sH[CUR][3][frow][g8];                              \
    }                                                                           \
    MF8(aQ0, 2); MF8(aQ1, 3);                                                   \
    __builtin_amdgcn_sched_barrier(0);                                          \
    if (frow < 2) {                                                             \
      aQ0 = *(const bf16x8*)&sH[CUR][4][frow][g8];                              \
      aQ1 = *(const bf16x8*)&sH[CUR][5][frow][g8];                              \
    }                                                                           \
    MF8(aP0, 4); MF8(aP1, 5);                                                   \
    __builtin_amdgcn_sched_barrier(0);                                          \
    if (frow < 2) {                                                             \
      aP0 = *(const bf16x8*)&sH[CUR][6][frow][g8];                              \
      aP1 = *(const bf16x8*)&sH[CUR][7][frow][g8];                              \
    }                                                                           \
    MF8(aQ0, 6); MF8(aQ1, 7);                                                   \
    __builtin_amdgcn_sched_barrier(0);                                          \
    MF8(aP0, 8); MF8(aP1, 9);                                                   \
    /* D: col=lane&15, row=4g+j -> rows 0,1 live in g==0 lanes, j=0,1 */        \
    float t000 = tanh_scaled(acc00[0]);   /* row0 col 64w+2f      */            \
    float t010 = tanh_scaled(acc01[0]);   /* row0 col 64w+2f+1    */            \
    float t100 = tanh_scaled(acc10[0]);   /* row0 col 64w+32+2f   */            \
    float t110 = tanh_scaled(acc11[0]);   /* row0 col 64w+32+2f+1 */            \
    float t001 = tanh_scaled(acc00[1]);   /* row1 variants */                   \
    float t011 = tanh_scaled(acc01[1]);                                         \
    float t101 = tanh_scaled(acc10[1]);                                         \
    float t111 = tanh_scaled(acc11[1]);                                         \
    if (g == 0) {                                                               \
      unsigned int* hd_ = (unsigned int*)sH[(CUR) ^ 1];                         \
      hd_[((2 * wave + 0) * 2 + 0) * 16 + frow] = cvt_pk_bf16(t000, t010);      \
      hd_[((2 * wave + 0) * 2 + 1) * 16 + frow] = cvt_pk_bf16(t001, t011);      \
      hd_[((2 * wave + 1) * 2 + 0) * 16 + frow] = cvt_pk_bf16(t100, t110);      \
      hd_[((2 * wave + 1) * 2 + 1) * 16 + frow] = cvt_pk_bf16(t101, t111);      \
    }                                                                           \
    BARRIER();                                                                  \
  } while (0)

__global__ __launch_bounds__(NTHREADS)
__attribute__((amdgpu_waves_per_eu(1)))
void rnn_scan_kernel(const float* __restrict__ x,
                     const float* __restrict__ W_ih,
                     const float* __restrict__ b_ih,
                     const float* __restrict__ W_ho,
                     const float* __restrict__ b_ho,
                     float* __restrict__ out) {
  // Interleaved layout: [buf][chunk][row][32 elems]; element (r,c) of the
  // logical 2x256 h-panel lives at sH[buf][c>>5][r][c&31]. Masked A-read
  // (8 lanes: g=0..3, frow=0..1) hits bytes kt*128 + frow*64 + 16g ->
  // dword banks frow*16+4g: 8 distinct banks, conflict-free.
  __shared__ __align__(16) unsigned short sH[2][8][2][32];  // 2 x 1 KB
  __shared__ __align__(16) unsigned short sX[2][2][2][32];  // 2 x 256 B

  const int tid  = threadIdx.x;
  const int lane = tid & 63;
  const int wave = tid >> 6;          // 0..3
  const int b0   = blockIdx.x * 2;    // two batch rows per block

  const int g    = (lane >> 4) & 3;   // k-group within fragment
  const int g8   = g * 8;             // element offset within k-tile chunk
  const int frow = lane & 15;         // A-row (reads) / B,D tile-col

  // ---- Preload W_ih as B-fragments (bf16, pre-scaled by TSCALE).
  // Sub-tile (p,q): global col = 64*wave + 32p + 2*frow + q.
  // B-frag: lane (g,f) holds B[kt*32 + 8g + i][tile-col f].
  bf16x8 bw[10][2][2];
  float bias00, bias01, bias10, bias11;
#pragma unroll
  for (int p = 0; p < 2; ++p) {
#pragma unroll
    for (int q = 0; q < 2; ++q) {
      const int col = 64 * wave + 32 * p + 2 * frow + q;
      const float bb = b_ih[col] * TSCALE;
      if (p == 0 && q == 0) bias00 = bb;
      if (p == 0 && q == 1) bias01 = bb;
      if (p == 1 && q == 0) bias10 = bb;
      if (p == 1 && q == 1) bias11 = bb;
#pragma unroll
      for (int kt = 0; kt < 10; ++kt) {
        bf16x8 v;
#pragma unroll
        for (int i = 0; i < 8; ++i)
          v[i] = (short)f2bf(W_ih[(size_t)(kt * 32 + g * 8 + i) * HID + col] * TSCALE);
        bw[kt][p][q] = v;
      }
    }
  }

  // ---- x staging: wave 0, all 64 lanes: row = lane>>5, col-pair = lane&31.
  const int xrow = lane >> 5, xcp = lane & 31;
  const float* xstage = x + (size_t)(b0 + xrow) * SEQ * INP + xcp * 2;
  float2 xrA = make_float2(0.f, 0.f), xrB = make_float2(0.f, 0.f);

  // ---- Persistent A-frag registers (masked lanes keep stale copies).
  bf16x8 aP0 = {}, aP1 = {}, aQ0 = {}, aQ1 = {};

  // ---- Prologue: h(0)=0; stage x(0) -> sX[0]; xrA=x(1), xrB=x(2).
  if (tid < 256) ((unsigned int*)sH[0])[tid] = 0u;
  if (wave == 0) {
    float2 v0 = *(const float2*)&xstage[0];
    ((unsigned int*)sX[0])[((xcp >> 4) * 2 + xrow) * 16 + (xcp & 15)]
        = cvt_pk_bf16(v0.x, v0.y);
    xrA = *(const float2*)&xstage[(size_t)1 * INP];
    xrB = *(const float2*)&xstage[(size_t)2 * INP];
  }
  BARRIER();

  // ---- Main scan: unroll-2 -> static buffer flip + x-register rotation.
#pragma unroll 1
  for (int t = 0; t < SEQ; t += 2) {
    STEP(t,     0, xrA);
    STEP(t + 1, 1, xrB);
  }
  // SEQ even -> h_final in sH[0]

  // ---- Head: out[b0+r] = h_final @ W_ho + b_ho (2 rows x 10 cols).
  if (tid < 2 * CLS) {
    const int r = tid / CLS, cl = tid - r * CLS;
    float s = b_ho[cl];
#pragma unroll 8
    for (int k = 0; k < HID; ++k)
      s += bf2f(sH[0][k >> 5][r][k & 31]) * W_ho[(size_t)k * CLS + cl];
    out[(size_t)(b0 + r) * CLS + cl] = s;
  }
}

extern "C" void kernel_launch(void* const* d_in, const int* in_sizes, int n_in,
                              void* d_out, int out_size, void* d_ws, size_t ws_size,
                              hipStream_t stream) {
  const float* x    = (const float*)d_in[0];
  const float* W_ih = (const float*)d_in[1];
  const float* b_ih = (const float*)d_in[2];
  const float* W_ho = (const float*)d_in[3];
  const float* b_ho = (const float*)d_in[4];
  float* out = (float*)d_out;

  rnn_scan_kernel<<<BATCH / 2, NTHREADS, 0, stream>>>(x, W_ih, b_ih, W_ho, b_ho, out);
}

// Round 11
// 547.716 us; speedup vs baseline: 1.8105x; 1.0927x over previous
//
#include <hip/hip_runtime.h>
#include <hip/hip_bf16.h>

// CustomRNN: h_{t+1} = tanh([x_t | h_t] @ W_ih + b_ih), out = h_final @ W_ho + b_ho
// BATCH=512, SEQ=1024, IN=64, HID=256, CLS=10.
//
// 256 blocks x 1024 threads (16 waves = 4 waves/SIMD), TWO batch rows per
// block, one block per CU. Cost model fitted across R4/R8/R9/R10:
//   step_cyc ~= 19.4 * (MFMA per SIMD per step) + C_chain
// (19.4 cyc = per-SIMD pipe cost of one 16x16x32 MFMA: 2075 TF chip ubench /
// 1024 SIMDs). The 160 MFMA/block-step is partition-invariant -> pipe floor
// 776 cyc. R8 (2 waves/SIMD) measured C ~= 464; R10 (1 wave/SIMD) C ~= 626.
// This round: 16 waves sharing the SAME pipe work -> 4 waves/SIMD round-robin
// should hide most of each wave's serial chain (ds latency -> 5-deep MFMA
// chains -> tanh -> write) under the others' pipe time.
//
//  - Wave w owns cols [16w,16w+16) (1 n-tile): 10 B-frags = 40 VGPR, total
//    demand ~90 -> fits the 128-reg tier that 4 waves/SIMD requires.
//  - LDS interleaved [kt][row][32elem]; A-reads exec-masked to frow<2
//    (8 lanes, 8 distinct banks, conflict-free).
//  - Split accumulator chains (even/odd kt): dependent depth 5.
//  - x: 2-step register prefetch by wave 0 into tiny LDS panel.
//  - Barrier: raw `s_waitcnt lgkmcnt(0); s_barrier` (vmcnt stays in flight).

#define BATCH 512
#define SEQ   1024
#define INP   64
#define HID   256
#define CLS   10
#define NTHREADS 1024
#define TSCALE 2.8853900817779268f // 2*log2(e), folded into W_ih/b_ih

typedef short bf16x8 __attribute__((ext_vector_type(8)));
typedef float f32x4  __attribute__((ext_vector_type(4)));

static __device__ __forceinline__ unsigned short f2bf(float f) {
  __hip_bfloat16 h = __float2bfloat16(f);   // RNE
  return *reinterpret_cast<unsigned short*>(&h);
}
static __device__ __forceinline__ float bf2f(unsigned short b) {
  union { unsigned int u; float f; } v; v.u = ((unsigned int)b) << 16;
  return v.f;
}
static __device__ __forceinline__ unsigned int cvt_pk_bf16(float lo, float hi) {
  unsigned int r;
  asm("v_cvt_pk_bf16_f32 %0, %1, %2" : "=v"(r) : "v"(lo), "v"(hi));
  return r;
}
static __device__ __forceinline__ float fast_exp2(float x) {
#if __has_builtin(__builtin_amdgcn_exp2f)
  return __builtin_amdgcn_exp2f(x);
#else
  return __exp2f(x);
#endif
}
static __device__ __forceinline__ float fast_rcp(float x) {
#if __has_builtin(__builtin_amdgcn_rcpf)
  return __builtin_amdgcn_rcpf(x);
#else
  return 1.0f / x;
#endif
}
// pre-activation already scaled by 2*log2(e): tanh(x) = 1 - 2/(1 + exp2(s)).
static __device__ __forceinline__ float tanh_scaled(float s) {
  return 1.0f - 2.0f * fast_rcp(1.0f + fast_exp2(s));
}

#define MFMA16(A, B, C) __builtin_amdgcn_mfma_f32_16x16x32_bf16(A, B, C, 0, 0, 0)

// Drain LDS ops only; in-flight global x loads (vmcnt) stay pending.
#define BARRIER() asm volatile("s_waitcnt lgkmcnt(0)\n\ts_barrier" ::: "memory")

// One scan step (reads buf CUR, writes buf CUR^1, one barrier).
// aP0,aP1,aQ0,aQ1: persistent frag regs; masked lanes (frow>=2) keep stale
// data — harmless, D rows 2-15 are padding. Chains: acca = even kt, accb = odd.
#define STEP(T, CUR, XR) do {                                                   \
    /* stage x(T+1) (in XR, loaded 2 steps ago) -> sX[CUR^1]; XR = x(T+3) */    \
    if (wave == 0) {                                                            \
      ((unsigned int*)sX[(CUR) ^ 1])[((xcp >> 4) * 2 + xrow) * 16 + (xcp & 15)] \
          = cvt_pk_bf16(XR.x, XR.y);                                            \
      int tn_ = (T) + 3; tn_ = tn_ < SEQ ? tn_ : SEQ - 1;                       \
      XR = *(const float2*)&xstage[(size_t)tn_ * INP];                          \
    }                                                                           \
    f32x4 acca = {bias, bias, bias, bias};                                      \
    f32x4 accb = {0.f, 0.f, 0.f, 0.f};                                          \
    /* masked A-reads: only lanes frow<2 carry real rows */                     \
    if (frow < 2) {                                                             \
      aP0 = *(const bf16x8*)&sX[CUR][0][frow][g8];                              \
      aP1 = *(const bf16x8*)&sX[CUR][1][frow][g8];                              \
      aQ0 = *(const bf16x8*)&sH[CUR][0][frow][g8];                              \
      aQ1 = *(const bf16x8*)&sH[CUR][1][frow][g8];                              \
    }                                                                           \
    acca = MFMA16(aP0, bw[0], acca);                                            \
    accb = MFMA16(aP1, bw[1], accb);                                            \
    __builtin_amdgcn_sched_barrier(0);                                          \
    if (frow < 2) {                                                             \
      aP0 = *(const bf16x8*)&sH[CUR][2][frow][g8];                              \
      aP1 = *(const bf16x8*)&sH[CUR][3][frow][g8];                              \
    }                                                                           \
    acca = MFMA16(aQ0, bw[2], acca);                                            \
    accb = MFMA16(aQ1, bw[3], accb);                                            \
    __builtin_amdgcn_sched_barrier(0);                                          \
    if (frow < 2) {                                                             \
      aQ0 = *(const bf16x8*)&sH[CUR][4][frow][g8];                              \
      aQ1 = *(const bf16x8*)&sH[CUR][5][frow][g8];                              \
    }                                                                           \
    acca = MFMA16(aP0, bw[4], acca);                                            \
    accb = MFMA16(aP1, bw[5], accb);                                            \
    __builtin_amdgcn_sched_barrier(0);                                          \
    if (frow < 2) {                                                             \
      aP0 = *(const bf16x8*)&sH[CUR][6][frow][g8];                              \
      aP1 = *(const bf16x8*)&sH[CUR][7][frow][g8];                              \
    }                                                                           \
    acca = MFMA16(aQ0, bw[6], acca);                                            \
    accb = MFMA16(aQ1, bw[7], accb);                                            \
    __builtin_amdgcn_sched_barrier(0);                                          \
    acca = MFMA16(aP0, bw[8], acca);                                            \
    accb = MFMA16(aP1, bw[9], accb);                                            \
    /* D: col=lane&15, row=4g+j -> rows 0,1 live in g==0 lanes, j=0,1 */        \
    float t0 = tanh_scaled(acca[0] + accb[0]);   /* row0, col 16w+f */          \
    float t1 = tanh_scaled(acca[1] + accb[1]);   /* row1, col 16w+f */          \
    if (g == 0) {                                                               \
      unsigned short* hd_ = (unsigned short*)sH[(CUR) ^ 1];                     \
      /* col c = 16*wave+frow: chunk = wave>>1, c&31 = (wave&1)*16+frow */      \
      hd_[(wave >> 1) * 64 + 0 * 32 + (wave & 1) * 16 + frow] = f2bf(t0);       \
      hd_[(wave >> 1) * 64 + 1 * 32 + (wave & 1) * 16 + frow] = f2bf(t1);       \
    }                                                                           \
    BARRIER();                                                                  \
  } while (0)

__global__ __launch_bounds__(NTHREADS, 1)
void rnn_scan_kernel(const float* __restrict__ x,
                     const float* __restrict__ W_ih,
                     const float* __restrict__ b_ih,
                     const float* __restrict__ W_ho,
                     const float* __restrict__ b_ho,
                     float* __restrict__ out) {
  // Interleaved layout: [buf][chunk][row][32 elems]; element (r,c) of the
  // logical 2x256 h-panel lives at sH[buf][c>>5][r][c&31]. Masked A-read
  // (8 lanes: g=0..3, frow=0..1) hits bytes kt*128 + frow*64 + 16g ->
  // dword banks frow*16+4g: 8 distinct banks, conflict-free.
  __shared__ __align__(16) unsigned short sH[2][8][2][32];  // 2 x 1 KB
  __shared__ __align__(16) unsigned short sX[2][2][2][32];  // 2 x 256 B

  const int tid  = threadIdx.x;
  const int lane = tid & 63;
  const int wave = tid >> 6;          // 0..15
  const int b0   = blockIdx.x * 2;    // two batch rows per block

  const int g    = (lane >> 4) & 3;   // k-group within fragment
  const int g8   = g * 8;             // element offset within k-tile chunk
  const int frow = lane & 15;         // A-row (reads) / B,D tile-col

  // ---- Preload W_ih as B-fragments (bf16, pre-scaled by TSCALE).
  // Wave w owns cols [16w, 16w+16); lane col = 16w + frow.
  // B-frag: lane (g,f) holds B[kt*32 + 8g + i][tile-col f].
  bf16x8 bw[10];
  const int col = 16 * wave + frow;
  const float bias = b_ih[col] * TSCALE;
#pragma unroll
  for (int kt = 0; kt < 10; ++kt) {
    bf16x8 v;
#pragma unroll
    for (int i = 0; i < 8; ++i)
      v[i] = (short)f2bf(W_ih[(size_t)(kt * 32 + g * 8 + i) * HID + col] * TSCALE);
    bw[kt] = v;
  }

  // ---- x staging: wave 0, all 64 lanes: row = lane>>5, col-pair = lane&31.
  const int xrow = lane >> 5, xcp = lane & 31;
  const float* xstage = x + (size_t)(b0 + xrow) * SEQ * INP + xcp * 2;
  float2 xrA = make_float2(0.f, 0.f), xrB = make_float2(0.f, 0.f);

  // ---- Persistent A-frag registers (masked lanes keep stale copies).
  bf16x8 aP0 = {}, aP1 = {}, aQ0 = {}, aQ1 = {};

  // ---- Prologue: h(0)=0; stage x(0) -> sX[0]; xrA=x(1), xrB=x(2).
  if (tid < 256) ((unsigned int*)sH[0])[tid] = 0u;
  if (wave == 0) {
    float2 v0 = *(const float2*)&xstage[0];
    ((unsigned int*)sX[0])[((xcp >> 4) * 2 + xrow) * 16 + (xcp & 15)]
        = cvt_pk_bf16(v0.x, v0.y);
    xrA = *(const float2*)&xstage[(size_t)1 * INP];
    xrB = *(const float2*)&xstage[(size_t)2 * INP];
  }
  BARRIER();

  // ---- Main scan: unroll-2 -> static buffer flip + x-register rotation.
#pragma unroll 1
  for (int t = 0; t < SEQ; t += 2) {
    STEP(t,     0, xrA);
    STEP(t + 1, 1, xrB);
  }
  // SEQ even -> h_final in sH[0]

  // ---- Head: out[b0+r] = h_final @ W_ho + b_ho (2 rows x 10 cols).
  if (tid < 2 * CLS) {
    const int r = tid / CLS, cl = tid - r * CLS;
    float s = b_ho[cl];
#pragma unroll 8
    for (int k = 0; k < HID; ++k)
      s += bf2f(sH[0][k >> 5][r][k & 31]) * W_ho[(size_t)k * CLS + cl];
    out[(size_t)(b0 + r) * CLS + cl] = s;
  }
}

extern "C" void kernel_launch(void* const* d_in, const int* in_sizes, int n_in,
                              void* d_out, int out_size, void* d_ws, size_t ws_size,
                              hipStream_t stream) {
  const float* x    = (const float*)d_in[0];
  const float* W_ih = (const float*)d_in[1];
  const float* b_ih = (const float*)d_in[2];
  const float* W_ho = (const float*)d_in[3];
  const float* b_ho = (const float*)d_in[4];
  float* out = (float*)d_out;

  rnn_scan_kernel<<<BATCH / 2, NTHREADS, 0, stream>>>(x, W_ih, b_ih, W_ho, b_ho, out);
}

// Round 12
// 537.730 us; speedup vs baseline: 1.8441x; 1.0186x over previous
//
#include <hip/hip_runtime.h>
#include <hip/hip_bf16.h>

// CustomRNN: h_{t+1} = tanh([x_t | h_t] @ W_ih + b_ih), out = h_final @ W_ho + b_ho
// BATCH=512, SEQ=1024, IN=64, HID=256, CLS=10.
//
// 256 blocks x 512 threads (8 waves, 2/SIMD), TWO batch rows per block,
// 1 block/CU. R11's null (16 waves, 2x occupancy, same dur) proved the
// ~460-cyc non-pipe chain is COMMON-MODE (all waves stall together post-
// barrier on ds_read and pre-barrier in tanh/write) — TLP can't hide it.
// R12 trims the self-inflicted parts of the chain:
//  1. NO sched_barrier fences: compiler software-pipelines reads/MFMA/stage.
//  2. 6-deep A-frag prefetch (reads issued >=8 MFMAs ahead; 120-cyc LDS
//     latency covered). VGPR ~116 (must stay <=128 for the 2-wave/SIMD tier).
//  3. x-staging balanced across all 8 waves (8 lanes each) — no straggler.
//  4. No setprio (lockstep waves; m190 shows it hurts there).
// Carried from R8: W_ih register-resident (pre-scaled by 2*log2e, 20 B-frags
// = 80 VGPR/wave; wave w owns paired cols 32w+2f, +1), interleaved
// conflict-free LDS [kt][row][32], A-reads exec-masked to frow<2, split
// accumulator chains, raw lgkmcnt(0)-only barrier (vmcnt stays in flight).

#define BATCH 512
#define SEQ   1024
#define INP   64
#define HID   256
#define CLS   10
#define NTHREADS 512
#define TSCALE 2.8853900817779268f // 2*log2(e), folded into W_ih/b_ih

typedef short bf16x8 __attribute__((ext_vector_type(8)));
typedef float f32x4  __attribute__((ext_vector_type(4)));

static __device__ __forceinline__ unsigned short f2bf(float f) {
  __hip_bfloat16 h = __float2bfloat16(f);   // RNE
  return *reinterpret_cast<unsigned short*>(&h);
}
static __device__ __forceinline__ float bf2f(unsigned short b) {
  union { unsigned int u; float f; } v; v.u = ((unsigned int)b) << 16;
  return v.f;
}
static __device__ __forceinline__ unsigned int cvt_pk_bf16(float lo, float hi) {
  unsigned int r;
  asm("v_cvt_pk_bf16_f32 %0, %1, %2" : "=v"(r) : "v"(lo), "v"(hi));
  return r;
}
static __device__ __forceinline__ float fast_exp2(float x) {
#if __has_builtin(__builtin_amdgcn_exp2f)
  return __builtin_amdgcn_exp2f(x);
#else
  return __exp2f(x);
#endif
}
static __device__ __forceinline__ float fast_rcp(float x) {
#if __has_builtin(__builtin_amdgcn_rcpf)
  return __builtin_amdgcn_rcpf(x);
#else
  return 1.0f / x;
#endif
}
// pre-activation already scaled by 2*log2(e): tanh(x) = 1 - 2/(1 + exp2(s)).
static __device__ __forceinline__ float tanh_scaled(float s) {
  return 1.0f - 2.0f * fast_rcp(1.0f + fast_exp2(s));
}

#define MFMA16(A, B, C) __builtin_amdgcn_mfma_f32_16x16x32_bf16(A, B, C, 0, 0, 0)

// Drain LDS ops only; in-flight global x loads (vmcnt) stay pending.
#define BARRIER() asm volatile("s_waitcnt lgkmcnt(0)\n\ts_barrier" ::: "memory")

// One scan step (reads buf CUR, writes buf CUR^1, one barrier).
// fA..fF: 6 rotating frag regs (masked lanes keep stale data — harmless,
// D rows 2-15 are padding). Chains: acc*a = even kt, acc*b = odd kt.
// No sched_barrier fences: compiler is free to software-pipeline.
#define STEP(T, CUR, XR) do {                                                   \
    /* balanced stage: each wave's lanes 0-7 stage one u32 of x(T+1) and    */ \
    /* issue the global load of x(T+3) (vmcnt never drained by BARRIER).    */ \
    if (lane < 8) {                                                             \
      ((unsigned int*)sX[(CUR) ^ 1])[((scp >> 4) * 2 + srow) * 16 + (scp & 15)] \
          = cvt_pk_bf16(XR.x, XR.y);                                            \
      int tn_ = (T) + 3; tn_ = tn_ < SEQ ? tn_ : SEQ - 1;                       \
      XR = *(const float2*)&xstage[(size_t)tn_ * INP];                          \
    }                                                                           \
    f32x4 acc0a = {bias0, bias0, 0.f, 0.f};                                     \
    f32x4 acc1a = {bias1, bias1, 0.f, 0.f};                                     \
    f32x4 acc0b = {0.f, 0.f, 0.f, 0.f};                                         \
    f32x4 acc1b = {0.f, 0.f, 0.f, 0.f};                                         \
    /* masked A-reads, 6-deep prefetch: only lanes frow<2 carry real rows */    \
    if (frow < 2) {                                                             \
      fA = *(const bf16x8*)&sX[CUR][0][frow][g8];                               \
      fB = *(const bf16x8*)&sX[CUR][1][frow][g8];                               \
      fC = *(const bf16x8*)&sH[CUR][0][frow][g8];                               \
      fD = *(const bf16x8*)&sH[CUR][1][frow][g8];                               \
      fE = *(const bf16x8*)&sH[CUR][2][frow][g8];                               \
      fF = *(const bf16x8*)&sH[CUR][3][frow][g8];                               \
    }                                                                           \
    acc0a = MFMA16(fA, bw[0][0], acc0a); acc1a = MFMA16(fA, bw[0][1], acc1a);   \
    acc0b = MFMA16(fB, bw[1][0], acc0b); acc1b = MFMA16(fB, bw[1][1], acc1b);   \
    if (frow < 2) {                                                             \
      fA = *(const bf16x8*)&sH[CUR][4][frow][g8];                               \
      fB = *(const bf16x8*)&sH[CUR][5][frow][g8];                               \
    }                                                                           \
    acc0a = MFMA16(fC, bw[2][0], acc0a); acc1a = MFMA16(fC, bw[2][1], acc1a);   \
    acc0b = MFMA16(fD, bw[3][0], acc0b); acc1b = MFMA16(fD, bw[3][1], acc1b);   \
    if (frow < 2) {                                                             \
      fC = *(const bf16x8*)&sH[CUR][6][frow][g8];                               \
      fD = *(const bf16x8*)&sH[CUR][7][frow][g8];                               \
    }                                                                           \
    acc0a = MFMA16(fE, bw[4][0], acc0a); acc1a = MFMA16(fE, bw[4][1], acc1a);   \
    acc0b = MFMA16(fF, bw[5][0], acc0b); acc1b = MFMA16(fF, bw[5][1], acc1b);   \
    acc0a = MFMA16(fA, bw[6][0], acc0a); acc1a = MFMA16(fA, bw[6][1], acc1a);   \
    acc0b = MFMA16(fB, bw[7][0], acc0b); acc1b = MFMA16(fB, bw[7][1], acc1b);   \
    acc0a = MFMA16(fC, bw[8][0], acc0a); acc1a = MFMA16(fC, bw[8][1], acc1a);   \
    acc0b = MFMA16(fD, bw[9][0], acc0b); acc1b = MFMA16(fD, bw[9][1], acc1b);   \
    /* D: col=lane&15, row=4g+j -> rows 0,1 live in g==0 lanes, j=0,1 */        \
    float t00 = tanh_scaled(acc0a[0] + acc0b[0]);   /* row0, col 32w+2f   */    \
    float t10 = tanh_scaled(acc1a[0] + acc1b[0]);   /* row0, col 32w+2f+1 */    \
    float t01 = tanh_scaled(acc0a[1] + acc0b[1]);   /* row1, col 32w+2f   */    \
    float t11 = tanh_scaled(acc1a[1] + acc1b[1]);   /* row1, col 32w+2f+1 */    \
    if (g == 0) {                                                               \
      unsigned int* hd_ = (unsigned int*)sH[(CUR) ^ 1];                         \
      hd_[wave * 32 + frow]      = cvt_pk_bf16(t00, t10);   /* row 0 */         \
      hd_[wave * 32 + 16 + frow] = cvt_pk_bf16(t01, t11);   /* row 1 */         \
    }                                                                           \
    BARRIER();                                                                  \
  } while (0)

__global__ __launch_bounds__(NTHREADS, 2)
void rnn_scan_kernel(const float* __restrict__ x,
                     const float* __restrict__ W_ih,
                     const float* __restrict__ b_ih,
                     const float* __restrict__ W_ho,
                     const float* __restrict__ b_ho,
                     float* __restrict__ out) {
  // Interleaved layout: [buf][chunk][row][32 elems]; element (r,c) of the
  // logical 2x256 h-panel lives at sH[buf][c>>5][r][c&31]. Masked A-read
  // (8 lanes: g=0..3, frow=0..1) hits bytes kt*128 + frow*64 + 16g ->
  // dword banks frow*16+4g: 8 distinct banks, conflict-free.
  __shared__ __align__(16) unsigned short sH[2][8][2][32];  // 2 x 1 KB
  __shared__ __align__(16) unsigned short sX[2][2][2][32];  // 2 x 256 B

  const int tid  = threadIdx.x;
  const int lane = tid & 63;
  const int wave = tid >> 6;          // 0..7
  const int b0   = blockIdx.x * 2;    // two batch rows per block

  const int g    = (lane >> 4) & 3;   // k-group within fragment
  const int g8   = g * 8;             // element offset within k-tile chunk
  const int frow = lane & 15;         // A-row (reads) / B,D tile-col

  // ---- Preload W_ih as B-fragments (bf16, pre-scaled by TSCALE).
  // Tile q: global col = 32*wave + 2*frow + q. Lane (g,f): B[kt*32+8g+i][f].
  bf16x8 bw[10][2];
  const int colE = 32 * wave + 2 * frow;
  const float bias0 = b_ih[colE] * TSCALE;
  const float bias1 = b_ih[colE + 1] * TSCALE;
#pragma unroll
  for (int q = 0; q < 2; ++q) {
#pragma unroll
    for (int kt = 0; kt < 10; ++kt) {
      bf16x8 v;
#pragma unroll
      for (int i = 0; i < 8; ++i)
        v[i] = (short)f2bf(W_ih[(size_t)(kt * 32 + g * 8 + i) * HID + colE + q] * TSCALE);
      bw[kt][q] = v;
    }
  }

  // ---- x staging, balanced: wave w lanes 0-7 own slot = 8w + lane
  // (slot -> row = slot>>5, col-pair = slot&31).
  const int slot = wave * 8 + (lane & 7);
  const int srow = slot >> 5, scp = slot & 31;
  const float* xstage = x + (size_t)(b0 + srow) * SEQ * INP + scp * 2;
  float2 xrA = make_float2(0.f, 0.f), xrB = make_float2(0.f, 0.f);

  // ---- Persistent A-frag registers (masked lanes keep stale copies).
  bf16x8 fA = {}, fB = {}, fC = {}, fD = {}, fE = {}, fF = {};

  // ---- Prologue: h(0)=0; stage x(0) -> sX[0]; xrA=x(1), xrB=x(2).
  if (tid < 256) ((unsigned int*)sH[0])[tid] = 0u;
  if (lane < 8) {
    float2 v0 = *(const float2*)&xstage[0];
    ((unsigned int*)sX[0])[((scp >> 4) * 2 + srow) * 16 + (scp & 15)]
        = cvt_pk_bf16(v0.x, v0.y);
    xrA = *(const float2*)&xstage[(size_t)1 * INP];
    xrB = *(const float2*)&xstage[(size_t)2 * INP];
  }
  BARRIER();

  // ---- Main scan: unroll-2 -> static buffer flip + x-register rotation.
#pragma unroll 1
  for (int t = 0; t < SEQ; t += 2) {
    STEP(t,     0, xrA);
    STEP(t + 1, 1, xrB);
  }
  // SEQ even -> h_final in sH[0]

  // ---- Head: out[b0+r] = h_final @ W_ho + b_ho (2 rows x 10 cols).
  if (tid < 2 * CLS) {
    const int r = tid / CLS, cl = tid - r * CLS;
    float s = b_ho[cl];
#pragma unroll 8
    for (int k = 0; k < HID; ++k)
      s += bf2f(sH[0][k >> 5][r][k & 31]) * W_ho[(size_t)k * CLS + cl];
    out[(size_t)(b0 + r) * CLS + cl] = s;
  }
}

extern "C" void kernel_launch(void* const* d_in, const int* in_sizes, int n_in,
                              void* d_out, int out_size, void* d_ws, size_t ws_size,
                              hipStream_t stream) {
  const float* x    = (const float*)d_in[0];
  const float* W_ih = (const float*)d_in[1];
  const float* b_ih = (const float*)d_in[2];
  const float* W_ho = (const float*)d_in[3];
  const float* b_ho = (const float*)d_in[4];
  float* out = (float*)d_out;

  rnn_scan_kernel<<<BATCH / 2, NTHREADS, 0, stream>>>(x, W_ih, b_ih, W_ho, b_ho, out);
}